// Round 7
// baseline (583.976 us; speedup 1.0000x reference)
//
#include <hip/hip_runtime.h>
#include <stdint.h>
#include <math.h>

// ---------------------------------------------------------------------------
// GraphDistillOperatorWithEdgeWeight, N=8192, F=256, OUT=256
//
//   E_ij = exp(5*adj_ij), E_ii = 0 ; s_i = sum_j E_ij ; a = E/s
//   agg = a@feat ; kagg = a@key
//   out1 = tanh(Xcat @ W1 + c1),  Xcat=[feat|agg],  W1=[[W_o],[0]] - W_d@W_o
//   out2 = tanh(Kcat @ W2 + c2),  Kcat=[key|kagg],  W2=[[W_ao],[W_a@W_ao]]
//
// Round change (producer/consumer wave specialization in exp_gemm):
//  8-wave block, 1/CU. Waves 0-3 PRODUCE: adj loads (4-deep reg ring,
//  vmcnt(8)), exp, mask, rowsum, sA writes. Waves 4-7 CONSUME: per-wave
//  4-slot LDS B-ring via global_load_lds (clean vm queue -> vmcnt(24),
//  fill->use distance 2 phases), ds_read + MFMA + Upart store. 1P+1C per
//  SIMD -> VALU pipe and MFMA pipe genuinely concurrent (m114), instead of
//  round 6's lockstep stage->MFMA serialization (measured: dur = SUM of
//  pipe budgets). M=64 halves B-L2 traffic vs round 6. Scalar role branch
//  via readfirstlane; barrier counts match (33 per role).
// ---------------------------------------------------------------------------

typedef __attribute__((ext_vector_type(4)))  short bf16x4_t;
typedef __attribute__((ext_vector_type(8)))  short bf16x8_t;
typedef __attribute__((ext_vector_type(4)))  float f32x4_t;
typedef __attribute__((ext_vector_type(16))) float f32x16_t;

#define MFMA32(A, B, C) __builtin_amdgcn_mfma_f32_32x32x16_bf16(A, B, C, 0, 0, 0)
#define MFMA16(A, B, C) __builtin_amdgcn_mfma_f32_16x16x32_bf16(A, B, C, 0, 0, 0)

__device__ __forceinline__ unsigned short f2bf(float x) {
    union { float f; unsigned u; } c; c.f = x;
    unsigned u = c.u;
    return (unsigned short)((u + 0x7fffu + ((u >> 16) & 1u)) >> 16);  // RNE
}
__device__ __forceinline__ unsigned pack2bf(float a, float b) {
    return (unsigned)f2bf(a) | ((unsigned)f2bf(b) << 16);
}
__device__ __forceinline__ float bflo(unsigned u) {
    union { unsigned u; float f; } c; c.u = u << 16; return c.f;
}
__device__ __forceinline__ float bfhi(unsigned u) {
    union { unsigned u; float f; } c; c.u = u & 0xffff0000u; return c.f;
}
// exp(5x) = 2^(5*log2(e)*x), single v_exp_f32
__device__ __forceinline__ float exp5(float x) {
    return __builtin_amdgcn_exp2f(7.2134752f * x);
}

// async global->LDS, 16B per lane: LDS dst = uniform base + lane*16
__device__ __forceinline__ void gll16(const unsigned short* g, unsigned short* l) {
    __builtin_amdgcn_global_load_lds(
        (const __attribute__((address_space(1))) unsigned int*)(g),
        (__attribute__((address_space(3))) unsigned int*)(l), 16, 0, 0);
}

// ---------------------------------------------------------------------------
// transpose_blob + fused pack: src[8192][256] f32 -> Xtb fragment blobs AND
// packdst[:, 0:128] bf16-pair halves.
// Blob (j = k/32, c32): 1024 shorts, short idx = s*512 + lane*8 + e, where
// lane = ((k>>3)&1)*32 + (col&31), s = (k>>4)&1, e = k&7.
// grid = (256 k-tiles, 8 col-tiles), block = 256.
// ---------------------------------------------------------------------------
__global__ __launch_bounds__(256) void transpose_blob(
    const float* __restrict__ src, unsigned short* __restrict__ Xtb,
    unsigned* __restrict__ packdst, int c32base)
{
    __shared__ float tile[32][33];
    const int t = threadIdx.x;
    const int x = t & 31, y4 = (t >> 5) * 4;
    const int r0 = blockIdx.x * 32, c0 = blockIdx.y * 32;
#pragma unroll
    for (int i = 0; i < 4; ++i)
        tile[y4 + i][x] = src[(size_t)(r0 + y4 + i) * 256 + c0 + x];
    __syncthreads();
    const int s = t >> 7, lane = (t >> 1) & 63, e0 = (t & 1) * 4;
    const int kl = s * 16 + (lane >> 5) * 8 + e0;   // k-local 0..31
    const int cl = lane & 31;                        // col-local
    unsigned short* blob = Xtb + ((size_t)blockIdx.x * 16 + (c0 >> 5) + c32base) * 1024;
    uint2 v;
    v.x = pack2bf(tile[kl][cl],     tile[kl + 1][cl]);
    v.y = pack2bf(tile[kl + 2][cl], tile[kl + 3][cl]);
    *(uint2*)(blob + t * 4) = v;
    // pack write (XcatN/Kcat cols 0..255 as bf16 pairs)
    const int prow = t >> 3, pc = t & 7;
    unsigned* pd = packdst + (size_t)(r0 + prow) * 256 + (c0 >> 1) + pc * 2;
    pd[0] = pack2bf(tile[prow][pc * 4 + 0], tile[prow][pc * 4 + 1]);
    pd[1] = pack2bf(tile[prow][pc * 4 + 2], tile[prow][pc * 4 + 3]);
}

// ---------------------------------------------------------------------------
// Weight composition, bias fold included (k==512 row computes the c-vector).
// grid = 513.
// ---------------------------------------------------------------------------
__global__ __launch_bounds__(256) void compose1(
    const float* __restrict__ W_d, const float* __restrict__ W_o,
    const float* __restrict__ b_d, const float* __restrict__ b_o,
    unsigned short* __restrict__ W1t, float* __restrict__ c1)
{
    __shared__ float wrow[256];
    const int k = blockIdx.x, t = threadIdx.x;
    const float* srcrow = (k < 512) ? (W_d + (size_t)k * 256) : b_d;
    wrow[t] = srcrow[t];
    __syncthreads();
    float acc = 0.f;
#pragma unroll 8
    for (int m = 0; m < 256; ++m) acc = fmaf(wrow[m], W_o[(size_t)m * 256 + t], acc);
    if (k < 512)
        W1t[(size_t)t * 512 + k] = f2bf((k < 256 ? W_o[(size_t)k * 256 + t] : 0.f) - acc);
    else
        c1[t] = b_o[t] - acc;
}

__global__ __launch_bounds__(256) void compose2(
    const float* __restrict__ W_a, const float* __restrict__ W_ao,
    const float* __restrict__ b_a, const float* __restrict__ b_ao,
    unsigned short* __restrict__ W2t, float* __restrict__ c2)
{
    __shared__ float wrow[256];
    const int k = blockIdx.x, t = threadIdx.x;
    if (k < 256) {
        W2t[(size_t)t * 512 + k] = f2bf(W_ao[(size_t)k * 256 + t]);
        return;
    }
    const float* srcrow = (k < 512) ? (W_a + (size_t)(k - 256) * 256) : b_a;
    wrow[t] = srcrow[t];
    __syncthreads();
    float acc = 0.f;
#pragma unroll 8
    for (int m = 0; m < 256; ++m) acc = fmaf(wrow[m], W_ao[(size_t)m * 256 + t], acc);
    if (k < 512) W2t[(size_t)t * 512 + k] = f2bf(acc);
    else         c2[t] = b_ao[t] + acc;
}

// ---------------------------------------------------------------------------
// exp_gemm: Upart[h] = bf16( E_slice @ [feat|key] ), rowsum partials f32.
// grid = 512 (128 rowblocks x 4 K-split), block = 512 (8 waves: 4P + 4C).
// Block tile: 64 rows x 512 cols, K-slice 2048, 32 phases of 2 k-steps.
// Producers (w<4): adj 4-chunk reg ring (vmcnt(8)), exp->sA double buffer.
// Consumers (w>=4): wave tile 64x128, per-wave 4-slot x 8KB LDS B-ring via
// global_load_lds, counted vmcnt(24) (clean queue: only B fills), 16 MFMA/j.
// LDS: sA 18432 + sB 131072 = 149504 B -> 1 block/CU.
// ---------------------------------------------------------------------------
#define ROWS 64
#define NPH 32      // phases of 2 k-steps
#define ASTRIDE 36  // padded LDS row stride (shorts)

__global__ __launch_bounds__(512, 2) void exp_gemm(
    const float* __restrict__ adj, const unsigned short* __restrict__ Xtb,
    unsigned* __restrict__ UpartB, float* __restrict__ sSp)
{
    __shared__ unsigned short sA[2][2][ROWS * ASTRIDE];  // 18432 B
    __shared__ unsigned short sB[4][4][4096];            // 131072 B (4 C-waves x 4 slots x 8KB)

    const int t = threadIdx.x;
    const int w = t >> 6, lane = t & 63, q = lane >> 5, l31 = lane & 31;
    // XCD-affine decode: each XCD owns ONE h-slice (2MB Xtb hot in its L2)
    const int xcd = blockIdx.x & 7;
    const int h = xcd >> 1;
    const int rb = ((blockIdx.x >> 3) << 1) | (xcd & 1);   // 0..127
    const int row0 = rb * ROWS;
    const int kbase = h * 2048, jbase = h * 64;

    if (__builtin_amdgcn_readfirstlane(w) < 4) {
        // ================= PRODUCER (waves 0-3) =================
        const int srow = t >> 2;          // 0..63 (4 threads per row)
        const int skoff = (t & 3) * 8;    // float offset within 32-k step
        const int sgrow = row0 + srow;
        const float* adj_row = adj + (size_t)sgrow * 8192 + kbase + skoff;
        const int swoff = srow * ASTRIDE + skoff;
        float rs = 0.f;
        float4 qa[4][4];  // ring: [chunk&3][ks*2 + half], chunk = 2 k-steps

        auto loadAdj = [&](int cidx) {
            float4* d = qa[cidx & 3];
            const float* base = adj_row + (size_t)cidx * 64;
            d[0] = *(const float4*)(base + 0);
            d[1] = *(const float4*)(base + 4);
            d[2] = *(const float4*)(base + 32);
            d[3] = *(const float4*)(base + 36);
        };
        auto stageChunk = [&](int cidx, int buf) {
            const float4* v = qa[cidx & 3];
#pragma unroll
            for (int ks = 0; ks < 2; ++ks) {
                const float4 a = v[ks * 2], b = v[ks * 2 + 1];
                float e[8];
                e[0] = exp5(a.x); e[1] = exp5(a.y); e[2] = exp5(a.z); e[3] = exp5(a.w);
                e[4] = exp5(b.x); e[5] = exp5(b.y); e[6] = exp5(b.z); e[7] = exp5(b.w);
                const int gk = kbase + (cidx * 2 + ks) * 32 + skoff;
#pragma unroll
                for (int i = 0; i < 8; ++i)
                    if (gk + i == sgrow) e[i] = 0.f;   // diagonal mask
                rs += ((e[0] + e[1]) + (e[2] + e[3])) + ((e[4] + e[5]) + (e[6] + e[7]));
                uint2 p0, p1;
                p0.x = pack2bf(e[0], e[1]); p0.y = pack2bf(e[2], e[3]);
                p1.x = pack2bf(e[4], e[5]); p1.y = pack2bf(e[6], e[7]);
                *(uint2*)(&sA[buf][ks][swoff])     = p0;
                *(uint2*)(&sA[buf][ks][swoff + 4]) = p1;
            }
        };

        // prologue: chunks 0..3 in flight; stage chunk 0
        loadAdj(0); loadAdj(1); loadAdj(2); loadAdj(3);
        asm volatile("s_waitcnt vmcnt(12)" ::: "memory");
        stageChunk(0, 0);
        asm volatile("s_waitcnt lgkmcnt(0)\n\ts_barrier" ::: "memory");

        for (int c = 0; c < NPH; ++c) {
            if (c + 1 < NPH) {
                asm volatile("s_waitcnt vmcnt(8)" ::: "memory");  // chunk c+1 ready
                stageChunk(c + 1, (c + 1) & 1);
            }
            loadAdj((c + 4) & 31);   // wrapped tail loads keep counts uniform
            asm volatile("s_waitcnt lgkmcnt(0)\n\ts_barrier" ::: "memory");
        }

        // rowsum partial: 4 stager threads per row
        rs += __shfl_xor(rs, 1);
        rs += __shfl_xor(rs, 2);
        if ((t & 3) == 0) sSp[h * 8192 + sgrow] = rs;
    } else {
        // ================= CONSUMER (waves 4-7) =================
        const int cw = w - 4;   // 0..3, owns cols cw*128..cw*128+127
        const unsigned short* XtbW = Xtb + (size_t)jbase * 16384
                                   + (size_t)cw * 4096 + lane * 8;
        unsigned short* const sBw = &sB[cw][0][0];

        f32x16_t acc[2][4];
#pragma unroll
        for (int mt = 0; mt < 2; ++mt)
#pragma unroll
            for (int ct = 0; ct < 4; ++ct)
#pragma unroll
                for (int e = 0; e < 16; ++e) acc[mt][ct][e] = 0.f;

        auto issueB = [&](int jn, int slot) {  // 8 vm ops, 8KB into ring slot
            const unsigned short* src = XtbW + (size_t)jn * 16384;
            unsigned short* dst = sBw + slot * 4096;
#pragma unroll
            for (int k4 = 0; k4 < 8; ++k4)
                gll16(src + k4 * 512, dst + k4 * 512);
        };
        // read slot, refill it with jnext (ordered by lgkmcnt(0)), then MFMA
        auto consume = [&](int buf, int u, int slot, int jnext) {
            const unsigned short* sbp = sBw + slot * 4096 + lane * 8;
            bf16x8_t bfr[4][2];
#pragma unroll
            for (int ct = 0; ct < 4; ++ct)
#pragma unroll
                for (int s = 0; s < 2; ++s)
                    bfr[ct][s] = *(const bf16x8_t*)(sbp + ct * 1024 + s * 512);
            const unsigned short* sa = &sA[buf][u][0] + l31 * ASTRIDE + q * 8;
            bf16x8_t af[2][2];
#pragma unroll
            for (int mt = 0; mt < 2; ++mt)
#pragma unroll
                for (int s = 0; s < 2; ++s) {
                    const unsigned short* p = sa + mt * (32 * ASTRIDE) + s * 16;
                    bf16x4_t lo = *(const bf16x4_t*)p;
                    bf16x4_t hi = *(const bf16x4_t*)(p + 4);
                    af[mt][s] = __builtin_shufflevector(lo, hi, 0, 1, 2, 3, 4, 5, 6, 7);
                }
            asm volatile("s_waitcnt lgkmcnt(0)" ::: "memory");  // slot reads done
            issueB(jnext, slot);
            __builtin_amdgcn_s_setprio(1);
#pragma unroll
            for (int s = 0; s < 2; ++s)
#pragma unroll
                for (int mt = 0; mt < 2; ++mt)
#pragma unroll
                    for (int ct = 0; ct < 4; ++ct)
                        acc[mt][ct] = MFMA32(af[mt][s], bfr[ct][s], acc[mt][ct]);
            __builtin_amdgcn_s_setprio(0);
        };

        // prologue: fill 4 slots (j=0..3); match producer's 1 barrier
        issueB(0, 0); issueB(1, 1); issueB(2, 2); issueB(3, 3);
        asm volatile("s_barrier" ::: "memory");

        for (int c = 0; c < NPH; ++c) {
            const int buf = c & 1;
            const int j0 = 2 * c, j1 = 2 * c + 1;
            // clean queue: only B fills. 4 slots = 32 ops in flight,
            // wait vmcnt(24) -> oldest slot (8 ops) retired, distance 2 phases.
            asm volatile("s_waitcnt vmcnt(24)" ::: "memory");
            consume(buf, 0, j0 & 3, (j0 + 4) & 63);
            asm volatile("s_waitcnt vmcnt(24)" ::: "memory");
            consume(buf, 1, j1 & 3, (j1 + 4) & 63);
            asm volatile("s_waitcnt lgkmcnt(0)\n\ts_barrier" ::: "memory");
        }

        // blocked store: per-wave 16KB blob (64 rows x 128 cols).
        // uint idx = ((mt*4+ct)*8+ip)*64 + lane holds rows rlo/rlo+1 where
        // rlo = mt*32 + 2*(ip&1) + 8*(ip>>1) + 4*q, col = ct*32 + (lane&31).
        unsigned* up = UpartB + (((size_t)h * 128 + rb) * 4 + cw) * 4096 + lane;
#pragma unroll
        for (int mt = 0; mt < 2; ++mt)
#pragma unroll
            for (int ct = 0; ct < 4; ++ct)
#pragma unroll
                for (int ip = 0; ip < 8; ++ip)
                    up[(size_t)(((mt * 4 + ct) * 8) + ip) * 64] =
                        pack2bf(acc[mt][ct][2 * ip], acc[mt][ct][2 * ip + 1]);
    }
}

// ---------------------------------------------------------------------------
// finalize: sum 4 blocked bf16 partials, normalize; agg -> XcatN[:,256:512],
// kagg -> Kcat[:,256:512]. Blobs: [4 h][128 rb][4 cw][4096 uint] (64r x 128c).
// grid = 1024 (128 rowblocks x 8 col-groups of 64), block = 256.
// Col-group g: cw = g>>1, half hf = g&1 (cols cw*128 + hf*64 + 0..63).
// ---------------------------------------------------------------------------
__global__ __launch_bounds__(256) void finalize_agg(
    const unsigned* __restrict__ UpartB, const float* __restrict__ sSp,
    unsigned* __restrict__ XcatN, unsigned* __restrict__ Kcat)
{
    __shared__ float sT[64][65];
    __shared__ float sInv[64];

    const int t = threadIdx.x;
    const int rb = blockIdx.x >> 3, g = blockIdx.x & 7;
    const int cw = g >> 1, hf = g & 1;
    const int row0 = rb * 64;

    if (t < 64) {
        const int r = row0 + t;
        sInv[t] = 1.f / (sSp[r] + sSp[8192 + r] + sSp[16384 + r] + sSp[24576 + r]);
    }

    // decode: thread t covers uint index i, lanes l0..l0+7
    const int mt = t >> 7, c2 = (t >> 6) & 1, ip = (t >> 3) & 7;
    const int l0 = (t & 7) * 8;
    const int i = (mt * 4 + (2 * hf + c2)) * 8 + ip;
    const int qq = l0 >> 5;
    const int rlo = mt * 32 + 2 * (ip & 1) + 8 * (ip >> 1) + 4 * qq;
    const int cbase = c2 * 32 + (l0 & 31);

    float lo[8], hi[8];
#pragma unroll
    for (int j = 0; j < 8; ++j) { lo[j] = 0.f; hi[j] = 0.f; }
#pragma unroll
    for (int h = 0; h < 4; ++h) {
        const unsigned* src = UpartB + (((size_t)h * 128 + rb) * 4 + cw) * 4096
                              + (size_t)i * 64 + l0;
        const uint4 v0 = *(const uint4*)(src);
        const uint4 v1 = *(const uint4*)(src + 4);
        const unsigned vv[8] = { v0.x, v0.y, v0.z, v0.w, v1.x, v1.y, v1.z, v1.w };
#pragma unroll
        for (int j = 0; j < 8; ++j) { lo[j] += bflo(vv[j]); hi[j] += bfhi(vv[j]); }
    }
#pragma unroll
    for (int j = 0; j < 8; ++j) {
        sT[rlo][cbase + j]     = lo[j];
        sT[rlo + 1][cbase + j] = hi[j];
    }
    __syncthreads();

    // write: thread -> row = t>>2 (0..63), 16 f32 cols at (t&3)*16
    const int row = t >> 2, cg = (t & 3) * 16;
    const float inv = sInv[row];
    unsigned outv[8];
#pragma unroll
    for (int j = 0; j < 8; ++j)
        outv[j] = pack2bf(sT[row][cg + 2 * j] * inv, sT[row][cg + 2 * j + 1] * inv);
    unsigned* dst = (g < 4 ? XcatN : Kcat)
                    + (size_t)(row0 + row) * 256 + 128 + (g & 3) * 32 + (cg >> 1);
    *(uint4*)(dst)     = *(const uint4*)(outv);
    *(uint4*)(dst + 4) = *(const uint4*)(outv + 4);
}

// ---------------------------------------------------------------------------
// gemm_out (fused both problems): out[8192][256] f32 =
//   tanh(A[8192][512]bf16 @ Wt[256][512]^T + c).
// grid = 512 (2 problems x 256 Mtiles of 32), block = 256 (4 waves).
// ---------------------------------------------------------------------------
__global__ __launch_bounds__(256) void gemm_out(
    const unsigned short* __restrict__ Aa, const unsigned short* __restrict__ Wta,
    const float* __restrict__ ca,
    const unsigned short* __restrict__ Ab, const unsigned short* __restrict__ Wtb,
    const float* __restrict__ cb,
    float* __restrict__ outa, float* __restrict__ outb)
{
    __shared__ unsigned short sAm[32 * ASTRIDE];
    __shared__ unsigned short sB[256 * ASTRIDE];
    __shared__ float sBias[256];

    const int bid = blockIdx.x;
    const int prob = bid >> 8, tile = bid & 255;
    const unsigned short* A  = prob ? Ab  : Aa;
    const unsigned short* Wt = prob ? Wtb : Wta;
    const float* cvec        = prob ? cb  : ca;
    float* out               = prob ? outb : outa;

    const int t = threadIdx.x, w = t >> 6, lane = t & 63;
    const int m_lo = lane & 15, quad = lane >> 4;
    const int row0 = tile * 32;
    sBias[t] = cvec[t];

    f32x4_t acc[2][4];
#pragma unroll
    for (int a = 0; a < 2; ++a)
#pragma unroll
        for (int b = 0; b < 4; ++b)
#pragma unroll
            for (int e = 0; e < 4; ++e) acc[a][b][e] = 0.f;

    for (int ks = 0; ks < 16; ++ks) {
        const int k0 = ks * 32;
        __syncthreads();
        if (t < 128) {  // A tile 32x32
            bf16x8_t v = *(const bf16x8_t*)(A + (size_t)(row0 + (t >> 2)) * 512 + k0 + (t & 3) * 8);
            unsigned short* d = &sAm[(t >> 2) * ASTRIDE + (t & 3) * 8];
            *(bf16x4_t*)d       = __builtin_shufflevector(v, v, 0, 1, 2, 3);
            *(bf16x4_t*)(d + 4) = __builtin_shufflevector(v, v, 4, 5, 6, 7);
        }
        {               // B tile 256x32, thread t stages n-row t
            const unsigned short* src = Wt + (size_t)t * 512 + k0;
            unsigned short* d = &sB[t * ASTRIDE];
#pragma unroll
            for (int j = 0; j < 4; ++j) {
                bf16x8_t v = *(const bf16x8_t*)(src + j * 8);
                *(bf16x4_t*)(d + j * 8)     = __builtin_shufflevector(v, v, 0, 1, 2, 3);
                *(bf16x4_t*)(d + j * 8 + 4) = __builtin_shufflevector(v, v, 4, 5, 6, 7);
            }
        }
        __syncthreads();
        bf16x8_t a0, a1;
        {
            const unsigned short* p = &sAm[m_lo * ASTRIDE + quad * 8];
            bf16x4_t lo = *(const bf16x4_t*)p, hi = *(const bf16x4_t*)(p + 4);
            a0 = __builtin_shufflevector(lo, hi, 0, 1, 2, 3, 4, 5, 6, 7);
            p += 16 * ASTRIDE;
            lo = *(const bf16x4_t*)p; hi = *(const bf16x4_t*)(p + 4);
            a1 = __builtin_shufflevector(lo, hi, 0, 1, 2, 3, 4, 5, 6, 7);
        }
#pragma unroll
        for (int nt = 0; nt < 4; ++nt) {
            const unsigned short* p = &sB[(w * 64 + nt * 16 + m_lo) * ASTRIDE + quad * 8];
            bf16x4_t lo = *(const bf16x4_t*)p, hi = *(const bf16x4_t*)(p + 4);
            bf16x8_t b = __builtin_shufflevector(lo, hi, 0, 1, 2, 3, 4, 5, 6, 7);
            acc[0][nt] = MFMA16(a0, b, acc[0][nt]);
            acc[1][nt] = MFMA16(a1, b, acc[1][nt]);
        }
    }

#pragma unroll
    for (int mt = 0; mt < 2; ++mt)
#pragma unroll
        for (int nt = 0; nt < 4; ++nt) {
            const int col = w * 64 + nt * 16 + m_lo;
#pragma unroll
            for (int r = 0; r < 4; ++r) {
                const int row = row0 + mt * 16 + quad * 4 + r;
                out[(size_t)row * 256 + col] = tanhf(acc[mt][nt][r] + sBias[col]);
            }
        }
}

// ---------------------------------------------------------------------------
extern "C" void kernel_launch(void* const* d_in, const int* in_sizes, int n_in,
                              void* d_out, int out_size, void* d_ws, size_t ws_size,
                              hipStream_t stream) {
    const float* features = (const float*)d_in[0];
    const float* key      = (const float*)d_in[1];
    const float* adj      = (const float*)d_in[2];
    const float* W_d  = (const float*)d_in[3];
    const float* b_d  = (const float*)d_in[4];
    const float* W_o  = (const float*)d_in[5];
    const float* b_o  = (const float*)d_in[6];
    const float* W_a  = (const float*)d_in[7];
    const float* b_a  = (const float*)d_in[8];
    const float* W_ao = (const float*)d_in[9];
    const float* b_ao = (const float*)d_in[10];

    float* out1 = (float*)d_out;
    float* out2 = out1 + (size_t)8192 * 256;

    char* ws = (char*)d_ws;
    unsigned short* XcatN = (unsigned short*)(ws);                 // [8192][512] bf16, 8 MB
    unsigned short* Kcat  = (unsigned short*)(ws +  8388608);      // [8192][512] bf16, 8 MB
    unsigned short* Xtb   = (unsigned short*)(ws + 16777216);      // fragment blobs, 8 MB
    unsigned*       UpartB= (unsigned*)      (ws + 25165824);      // blocked [4][128][4][4096] u32, 32 MB
    float*          sSp   = (float*)         (ws + 58720256);      // [4][8192] f32
    unsigned short* W1t   = (unsigned short*)(ws + 58851328);      // [256][512] bf16
    unsigned short* W2t   = (unsigned short*)(ws + 59113472);      // [256][512] bf16
    float*          c1    = (float*)         (ws + 59375616);      // [256]
    float*          c2    = (float*)         (ws + 59376640);      // [256]

    dim3 blk(256);
    transpose_blob<<<dim3(256, 8), blk, 0, stream>>>(features, Xtb, (unsigned*)XcatN, 0);
    transpose_blob<<<dim3(256, 8), blk, 0, stream>>>(key, Xtb, (unsigned*)Kcat, 8);
    compose1<<<513, blk, 0, stream>>>(W_d, W_o, b_d, b_o, W1t, c1);
    compose2<<<513, blk, 0, stream>>>(W_a, W_ao, b_a, b_ao, W2t, c2);

    exp_gemm<<<512, dim3(512), 0, stream>>>(adj, Xtb, UpartB, sSp);
    finalize_agg<<<1024, blk, 0, stream>>>(UpartB, sSp,
                                           (unsigned*)XcatN, (unsigned*)Kcat);

    gemm_out<<<512, blk, 0, stream>>>(XcatN, W1t, c1, Kcat, W2t, c2, out1, out2);
}

// Round 8
// 513.987 us; speedup vs baseline: 1.1362x; 1.1362x over previous
//
#include <hip/hip_runtime.h>
#include <stdint.h>
#include <math.h>

// ---------------------------------------------------------------------------
// GraphDistillOperatorWithEdgeWeight, N=8192, F=256, OUT=256
//
//   E_ij = exp(5*adj_ij), E_ii = 0 ; s_i = sum_j E_ij ; a = E/s
//   agg = a@feat ; kagg = a@key
//   out1 = tanh(Xcat @ W1 + c1),  Xcat=[feat|agg],  W1=[[W_o],[0]] - W_d@W_o
//   out2 = tanh(Kcat @ W2 + c2),  Kcat=[key|kagg],  W2=[[W_ao],[W_a@W_ao]]
//
// Round change (scratch fix for the producer/consumer kernel):
//  Round 7's adj ring was a RUNTIME-INDEXED array qa[4][4] -> allocated in
//  scratch (rule: runtime-indexed ext_vector arrays spill), ~270 MB of
//  scratch W+R poisoned the P/C test (WRITE_SIZE 248 MB). This round: named
//  QAP qa0..qa3 registers threaded through a 4x-unrolled phase sequence
//  (round 6's proven pattern). Everything else identical to round 7:
//  waves 0-3 produce (adj->exp->sA), waves 4-7 consume (LDS B-ring via
//  global_load_lds, counted vmcnt(24), MFMA), 1P+1C per SIMD.
// ---------------------------------------------------------------------------

typedef __attribute__((ext_vector_type(4)))  short bf16x4_t;
typedef __attribute__((ext_vector_type(8)))  short bf16x8_t;
typedef __attribute__((ext_vector_type(4)))  float f32x4_t;
typedef __attribute__((ext_vector_type(16))) float f32x16_t;

#define MFMA32(A, B, C) __builtin_amdgcn_mfma_f32_32x32x16_bf16(A, B, C, 0, 0, 0)
#define MFMA16(A, B, C) __builtin_amdgcn_mfma_f32_16x16x32_bf16(A, B, C, 0, 0, 0)

__device__ __forceinline__ unsigned short f2bf(float x) {
    union { float f; unsigned u; } c; c.f = x;
    unsigned u = c.u;
    return (unsigned short)((u + 0x7fffu + ((u >> 16) & 1u)) >> 16);  // RNE
}
__device__ __forceinline__ unsigned pack2bf(float a, float b) {
    return (unsigned)f2bf(a) | ((unsigned)f2bf(b) << 16);
}
__device__ __forceinline__ float bflo(unsigned u) {
    union { unsigned u; float f; } c; c.u = u << 16; return c.f;
}
__device__ __forceinline__ float bfhi(unsigned u) {
    union { unsigned u; float f; } c; c.u = u & 0xffff0000u; return c.f;
}
// exp(5x) = 2^(5*log2(e)*x), single v_exp_f32
__device__ __forceinline__ float exp5(float x) {
    return __builtin_amdgcn_exp2f(7.2134752f * x);
}

// async global->LDS, 16B per lane: LDS dst = uniform base + lane*16
__device__ __forceinline__ void gll16(const unsigned short* g, unsigned short* l) {
    __builtin_amdgcn_global_load_lds(
        (const __attribute__((address_space(1))) unsigned int*)(g),
        (__attribute__((address_space(3))) unsigned int*)(l), 16, 0, 0);
}

// ---------------------------------------------------------------------------
// transpose_blob + fused pack: src[8192][256] f32 -> Xtb fragment blobs AND
// packdst[:, 0:128] bf16-pair halves.
// Blob (j = k/32, c32): 1024 shorts, short idx = s*512 + lane*8 + e, where
// lane = ((k>>3)&1)*32 + (col&31), s = (k>>4)&1, e = k&7.
// grid = (256 k-tiles, 8 col-tiles), block = 256.
// ---------------------------------------------------------------------------
__global__ __launch_bounds__(256) void transpose_blob(
    const float* __restrict__ src, unsigned short* __restrict__ Xtb,
    unsigned* __restrict__ packdst, int c32base)
{
    __shared__ float tile[32][33];
    const int t = threadIdx.x;
    const int x = t & 31, y4 = (t >> 5) * 4;
    const int r0 = blockIdx.x * 32, c0 = blockIdx.y * 32;
#pragma unroll
    for (int i = 0; i < 4; ++i)
        tile[y4 + i][x] = src[(size_t)(r0 + y4 + i) * 256 + c0 + x];
    __syncthreads();
    const int s = t >> 7, lane = (t >> 1) & 63, e0 = (t & 1) * 4;
    const int kl = s * 16 + (lane >> 5) * 8 + e0;   // k-local 0..31
    const int cl = lane & 31;                        // col-local
    unsigned short* blob = Xtb + ((size_t)blockIdx.x * 16 + (c0 >> 5) + c32base) * 1024;
    uint2 v;
    v.x = pack2bf(tile[kl][cl],     tile[kl + 1][cl]);
    v.y = pack2bf(tile[kl + 2][cl], tile[kl + 3][cl]);
    *(uint2*)(blob + t * 4) = v;
    // pack write (XcatN/Kcat cols 0..255 as bf16 pairs)
    const int prow = t >> 3, pc = t & 7;
    unsigned* pd = packdst + (size_t)(r0 + prow) * 256 + (c0 >> 1) + pc * 2;
    pd[0] = pack2bf(tile[prow][pc * 4 + 0], tile[prow][pc * 4 + 1]);
    pd[1] = pack2bf(tile[prow][pc * 4 + 2], tile[prow][pc * 4 + 3]);
}

// ---------------------------------------------------------------------------
// Weight composition, bias fold included (k==512 row computes the c-vector).
// grid = 513.
// ---------------------------------------------------------------------------
__global__ __launch_bounds__(256) void compose1(
    const float* __restrict__ W_d, const float* __restrict__ W_o,
    const float* __restrict__ b_d, const float* __restrict__ b_o,
    unsigned short* __restrict__ W1t, float* __restrict__ c1)
{
    __shared__ float wrow[256];
    const int k = blockIdx.x, t = threadIdx.x;
    const float* srcrow = (k < 512) ? (W_d + (size_t)k * 256) : b_d;
    wrow[t] = srcrow[t];
    __syncthreads();
    float acc = 0.f;
#pragma unroll 8
    for (int m = 0; m < 256; ++m) acc = fmaf(wrow[m], W_o[(size_t)m * 256 + t], acc);
    if (k < 512)
        W1t[(size_t)t * 512 + k] = f2bf((k < 256 ? W_o[(size_t)k * 256 + t] : 0.f) - acc);
    else
        c1[t] = b_o[t] - acc;
}

__global__ __launch_bounds__(256) void compose2(
    const float* __restrict__ W_a, const float* __restrict__ W_ao,
    const float* __restrict__ b_a, const float* __restrict__ b_ao,
    unsigned short* __restrict__ W2t, float* __restrict__ c2)
{
    __shared__ float wrow[256];
    const int k = blockIdx.x, t = threadIdx.x;
    if (k < 256) {
        W2t[(size_t)t * 512 + k] = f2bf(W_ao[(size_t)k * 256 + t]);
        return;
    }
    const float* srcrow = (k < 512) ? (W_a + (size_t)(k - 256) * 256) : b_a;
    wrow[t] = srcrow[t];
    __syncthreads();
    float acc = 0.f;
#pragma unroll 8
    for (int m = 0; m < 256; ++m) acc = fmaf(wrow[m], W_ao[(size_t)m * 256 + t], acc);
    if (k < 512) W2t[(size_t)t * 512 + k] = f2bf(acc);
    else         c2[t] = b_ao[t] + acc;
}

// ---------------------------------------------------------------------------
// exp_gemm: Upart[h] = bf16( E_slice @ [feat|key] ), rowsum partials f32.
// grid = 512 (128 rowblocks x 4 K-split), block = 512 (8 waves: 4P + 4C).
// Block tile: 64 rows x 512 cols, K-slice 2048, 32 phases of 2 k-steps.
// Producers (w<4): adj NAMED 4-chunk reg ring (vmcnt(8)), exp->sA dbuf.
// Consumers (w>=4): wave tile 64x128, per-wave 4-slot x 8KB LDS B-ring via
// global_load_lds, counted vmcnt(24) (clean queue: only B fills), 16 MFMA/j.
// LDS: sA 18432 + sB 131072 = 149504 B -> 1 block/CU.
// ---------------------------------------------------------------------------
#define ROWS 64
#define NPH 32      // phases of 2 k-steps
#define ASTRIDE 36  // padded LDS row stride (shorts)

struct QAP { float4 v[4]; };  // one chunk (2 k-steps x 8 floats) per thread

__global__ __launch_bounds__(512, 2) void exp_gemm(
    const float* __restrict__ adj, const unsigned short* __restrict__ Xtb,
    unsigned* __restrict__ UpartB, float* __restrict__ sSp)
{
    __shared__ unsigned short sA[2][2][ROWS * ASTRIDE];  // 18432 B
    __shared__ unsigned short sB[4][4][4096];            // 131072 B (4 C-waves x 4 slots x 8KB)

    const int t = threadIdx.x;
    const int w = t >> 6, lane = t & 63, q = lane >> 5, l31 = lane & 31;
    // XCD-affine decode: each XCD owns ONE h-slice (2MB Xtb hot in its L2)
    const int xcd = blockIdx.x & 7;
    const int h = xcd >> 1;
    const int rb = ((blockIdx.x >> 3) << 1) | (xcd & 1);   // 0..127
    const int row0 = rb * ROWS;
    const int kbase = h * 2048, jbase = h * 64;

    if (__builtin_amdgcn_readfirstlane(w) < 4) {
        // ================= PRODUCER (waves 0-3) =================
        const int srow = t >> 2;          // 0..63 (4 threads per row)
        const int skoff = (t & 3) * 8;    // float offset within 32-k step
        const int sgrow = row0 + srow;
        const float* adj_row = adj + (size_t)sgrow * 8192 + kbase + skoff;
        const int swoff = srow * ASTRIDE + skoff;
        float rs = 0.f;
        QAP qa0, qa1, qa2, qa3;  // NAMED ring entries -> register-resident

        auto loadAdj = [&](int cidx, QAP& d) {
            const float* base = adj_row + (size_t)cidx * 64;
            d.v[0] = *(const float4*)(base + 0);
            d.v[1] = *(const float4*)(base + 4);
            d.v[2] = *(const float4*)(base + 32);
            d.v[3] = *(const float4*)(base + 36);
        };
        auto stageChunk = [&](int cidx, const QAP& qq, int buf) {
#pragma unroll
            for (int ks = 0; ks < 2; ++ks) {
                const float4 a = qq.v[ks * 2], b = qq.v[ks * 2 + 1];
                float e[8];
                e[0] = exp5(a.x); e[1] = exp5(a.y); e[2] = exp5(a.z); e[3] = exp5(a.w);
                e[4] = exp5(b.x); e[5] = exp5(b.y); e[6] = exp5(b.z); e[7] = exp5(b.w);
                const int gk = kbase + (cidx * 2 + ks) * 32 + skoff;
#pragma unroll
                for (int i = 0; i < 8; ++i)
                    if (gk + i == sgrow) e[i] = 0.f;   // diagonal mask
                rs += ((e[0] + e[1]) + (e[2] + e[3])) + ((e[4] + e[5]) + (e[6] + e[7]));
                uint2 p0, p1;
                p0.x = pack2bf(e[0], e[1]); p0.y = pack2bf(e[2], e[3]);
                p1.x = pack2bf(e[4], e[5]); p1.y = pack2bf(e[6], e[7]);
                *(uint2*)(&sA[buf][ks][swoff])     = p0;
                *(uint2*)(&sA[buf][ks][swoff + 4]) = p1;
            }
        };
        // phase c: stage chunk c+1 (from qstg), refill qld with chunk c+4.
        // vm queue (4 ops/chunk): at the wait, chunks c+1..c+3 outstanding
        // (12 ops); vmcnt(8) retires chunk c+1's 4 ops.
        auto pphase = [&](int c, const QAP& qstg, QAP& qld) {
            if (c + 1 < NPH) {
                asm volatile("s_waitcnt vmcnt(8)" ::: "memory");
                stageChunk(c + 1, qstg, (c + 1) & 1);
            }
            loadAdj((c + 4) & 31, qld);   // wrapped tail keeps counts uniform
            asm volatile("s_waitcnt lgkmcnt(0)\n\ts_barrier" ::: "memory");
        };

        // prologue: chunks 0..3 in flight; stage chunk 0
        loadAdj(0, qa0); loadAdj(1, qa1); loadAdj(2, qa2); loadAdj(3, qa3);
        asm volatile("s_waitcnt vmcnt(12)" ::: "memory");
        stageChunk(0, qa0, 0);
        asm volatile("s_waitcnt lgkmcnt(0)\n\ts_barrier" ::: "memory");

        for (int c0 = 0; c0 < NPH; c0 += 4) {
            pphase(c0 + 0, qa1, qa0);
            pphase(c0 + 1, qa2, qa1);
            pphase(c0 + 2, qa3, qa2);
            pphase(c0 + 3, qa0, qa3);
        }

        // rowsum partial: 4 stager threads per row
        rs += __shfl_xor(rs, 1);
        rs += __shfl_xor(rs, 2);
        if ((t & 3) == 0) sSp[h * 8192 + sgrow] = rs;
    } else {
        // ================= CONSUMER (waves 4-7) =================
        const int cw = w - 4;   // 0..3, owns cols cw*128..cw*128+127
        const unsigned short* XtbW = Xtb + (size_t)jbase * 16384
                                   + (size_t)cw * 4096 + lane * 8;
        unsigned short* const sBw = &sB[cw][0][0];

        f32x16_t acc[2][4];
#pragma unroll
        for (int mt = 0; mt < 2; ++mt)
#pragma unroll
            for (int ct = 0; ct < 4; ++ct)
#pragma unroll
                for (int e = 0; e < 16; ++e) acc[mt][ct][e] = 0.f;

        auto issueB = [&](int jn, int slot) {  // 8 vm ops, 8KB into ring slot
            const unsigned short* src = XtbW + (size_t)jn * 16384;
            unsigned short* dst = sBw + slot * 4096;
#pragma unroll
            for (int k4 = 0; k4 < 8; ++k4)
                gll16(src + k4 * 512, dst + k4 * 512);
        };
        // read slot, refill it with jnext (ordered by lgkmcnt(0)), then MFMA
        auto consume = [&](int buf, int u, int slot, int jnext) {
            const unsigned short* sbp = sBw + slot * 4096 + lane * 8;
            bf16x8_t bfr[4][2];
#pragma unroll
            for (int ct = 0; ct < 4; ++ct)
#pragma unroll
                for (int s = 0; s < 2; ++s)
                    bfr[ct][s] = *(const bf16x8_t*)(sbp + ct * 1024 + s * 512);
            const unsigned short* sa = &sA[buf][u][0] + l31 * ASTRIDE + q * 8;
            bf16x8_t af[2][2];
#pragma unroll
            for (int mt = 0; mt < 2; ++mt)
#pragma unroll
                for (int s = 0; s < 2; ++s) {
                    const unsigned short* p = sa + mt * (32 * ASTRIDE) + s * 16;
                    bf16x4_t lo = *(const bf16x4_t*)p;
                    bf16x4_t hi = *(const bf16x4_t*)(p + 4);
                    af[mt][s] = __builtin_shufflevector(lo, hi, 0, 1, 2, 3, 4, 5, 6, 7);
                }
            asm volatile("s_waitcnt lgkmcnt(0)" ::: "memory");  // slot reads done
            issueB(jnext, slot);
            __builtin_amdgcn_s_setprio(1);
#pragma unroll
            for (int s = 0; s < 2; ++s)
#pragma unroll
                for (int mt = 0; mt < 2; ++mt)
#pragma unroll
                    for (int ct = 0; ct < 4; ++ct)
                        acc[mt][ct] = MFMA32(af[mt][s], bfr[ct][s], acc[mt][ct]);
            __builtin_amdgcn_s_setprio(0);
        };

        // prologue: fill 4 slots (j=0..3); match producer's 1 barrier
        issueB(0, 0); issueB(1, 1); issueB(2, 2); issueB(3, 3);
        asm volatile("s_barrier" ::: "memory");

        for (int c = 0; c < NPH; ++c) {
            const int buf = c & 1;
            const int j0 = 2 * c, j1 = 2 * c + 1;
            // clean queue: only B fills. 4 slots = 32 ops in flight,
            // wait vmcnt(24) -> oldest slot (8 ops) retired, distance 2 phases.
            asm volatile("s_waitcnt vmcnt(24)" ::: "memory");
            consume(buf, 0, j0 & 3, (j0 + 4) & 63);
            asm volatile("s_waitcnt vmcnt(24)" ::: "memory");
            consume(buf, 1, j1 & 3, (j1 + 4) & 63);
            asm volatile("s_waitcnt lgkmcnt(0)\n\ts_barrier" ::: "memory");
        }

        // blocked store: per-wave 16KB blob (64 rows x 128 cols).
        // uint idx = ((mt*4+ct)*8+ip)*64 + lane holds rows rlo/rlo+1 where
        // rlo = mt*32 + 2*(ip&1) + 8*(ip>>1) + 4*q, col = ct*32 + (lane&31).
        unsigned* up = UpartB + (((size_t)h * 128 + rb) * 4 + cw) * 4096 + lane;
#pragma unroll
        for (int mt = 0; mt < 2; ++mt)
#pragma unroll
            for (int ct = 0; ct < 4; ++ct)
#pragma unroll
                for (int ip = 0; ip < 8; ++ip)
                    up[(size_t)(((mt * 4 + ct) * 8) + ip) * 64] =
                        pack2bf(acc[mt][ct][2 * ip], acc[mt][ct][2 * ip + 1]);
    }
}

// ---------------------------------------------------------------------------
// finalize: sum 4 blocked bf16 partials, normalize; agg -> XcatN[:,256:512],
// kagg -> Kcat[:,256:512]. Blobs: [4 h][128 rb][4 cw][4096 uint] (64r x 128c).
// grid = 1024 (128 rowblocks x 8 col-groups of 64), block = 256.
// Col-group g: cw = g>>1, half hf = g&1 (cols cw*128 + hf*64 + 0..63).
// ---------------------------------------------------------------------------
__global__ __launch_bounds__(256) void finalize_agg(
    const unsigned* __restrict__ UpartB, const float* __restrict__ sSp,
    unsigned* __restrict__ XcatN, unsigned* __restrict__ Kcat)
{
    __shared__ float sT[64][65];
    __shared__ float sInv[64];

    const int t = threadIdx.x;
    const int rb = blockIdx.x >> 3, g = blockIdx.x & 7;
    const int cw = g >> 1, hf = g & 1;
    const int row0 = rb * 64;

    if (t < 64) {
        const int r = row0 + t;
        sInv[t] = 1.f / (sSp[r] + sSp[8192 + r] + sSp[16384 + r] + sSp[24576 + r]);
    }

    // decode: thread t covers uint index i, lanes l0..l0+7
    const int mt = t >> 7, c2 = (t >> 6) & 1, ip = (t >> 3) & 7;
    const int l0 = (t & 7) * 8;
    const int i = (mt * 4 + (2 * hf + c2)) * 8 + ip;
    const int qq = l0 >> 5;
    const int rlo = mt * 32 + 2 * (ip & 1) + 8 * (ip >> 1) + 4 * qq;
    const int cbase = c2 * 32 + (l0 & 31);

    float lo[8], hi[8];
#pragma unroll
    for (int j = 0; j < 8; ++j) { lo[j] = 0.f; hi[j] = 0.f; }
#pragma unroll
    for (int h = 0; h < 4; ++h) {
        const unsigned* src = UpartB + (((size_t)h * 128 + rb) * 4 + cw) * 4096
                              + (size_t)i * 64 + l0;
        const uint4 v0 = *(const uint4*)(src);
        const uint4 v1 = *(const uint4*)(src + 4);
        const unsigned vv[8] = { v0.x, v0.y, v0.z, v0.w, v1.x, v1.y, v1.z, v1.w };
#pragma unroll
        for (int j = 0; j < 8; ++j) { lo[j] += bflo(vv[j]); hi[j] += bfhi(vv[j]); }
    }
#pragma unroll
    for (int j = 0; j < 8; ++j) {
        sT[rlo][cbase + j]     = lo[j];
        sT[rlo + 1][cbase + j] = hi[j];
    }
    __syncthreads();

    // write: thread -> row = t>>2 (0..63), 16 f32 cols at (t&3)*16
    const int row = t >> 2, cg = (t & 3) * 16;
    const float inv = sInv[row];
    unsigned outv[8];
#pragma unroll
    for (int j = 0; j < 8; ++j)
        outv[j] = pack2bf(sT[row][cg + 2 * j] * inv, sT[row][cg + 2 * j + 1] * inv);
    unsigned* dst = (g < 4 ? XcatN : Kcat)
                    + (size_t)(row0 + row) * 256 + 128 + (g & 3) * 32 + (cg >> 1);
    *(uint4*)(dst)     = *(const uint4*)(outv);
    *(uint4*)(dst + 4) = *(const uint4*)(outv + 4);
}

// ---------------------------------------------------------------------------
// gemm_out (fused both problems): out[8192][256] f32 =
//   tanh(A[8192][512]bf16 @ Wt[256][512]^T + c).
// grid = 512 (2 problems x 256 Mtiles of 32), block = 256 (4 waves).
// ---------------------------------------------------------------------------
__global__ __launch_bounds__(256) void gemm_out(
    const unsigned short* __restrict__ Aa, const unsigned short* __restrict__ Wta,
    const float* __restrict__ ca,
    const unsigned short* __restrict__ Ab, const unsigned short* __restrict__ Wtb,
    const float* __restrict__ cb,
    float* __restrict__ outa, float* __restrict__ outb)
{
    __shared__ unsigned short sAm[32 * ASTRIDE];
    __shared__ unsigned short sB[256 * ASTRIDE];
    __shared__ float sBias[256];

    const int bid = blockIdx.x;
    const int prob = bid >> 8, tile = bid & 255;
    const unsigned short* A  = prob ? Ab  : Aa;
    const unsigned short* Wt = prob ? Wtb : Wta;
    const float* cvec        = prob ? cb  : ca;
    float* out               = prob ? outb : outa;

    const int t = threadIdx.x, w = t >> 6, lane = t & 63;
    const int m_lo = lane & 15, quad = lane >> 4;
    const int row0 = tile * 32;
    sBias[t] = cvec[t];

    f32x4_t acc[2][4];
#pragma unroll
    for (int a = 0; a < 2; ++a)
#pragma unroll
        for (int b = 0; b < 4; ++b)
#pragma unroll
            for (int e = 0; e < 4; ++e) acc[a][b][e] = 0.f;

    for (int ks = 0; ks < 16; ++ks) {
        const int k0 = ks * 32;
        __syncthreads();
        if (t < 128) {  // A tile 32x32
            bf16x8_t v = *(const bf16x8_t*)(A + (size_t)(row0 + (t >> 2)) * 512 + k0 + (t & 3) * 8);
            unsigned short* d = &sAm[(t >> 2) * ASTRIDE + (t & 3) * 8];
            *(bf16x4_t*)d       = __builtin_shufflevector(v, v, 0, 1, 2, 3);
            *(bf16x4_t*)(d + 4) = __builtin_shufflevector(v, v, 4, 5, 6, 7);
        }
        {               // B tile 256x32, thread t stages n-row t
            const unsigned short* src = Wt + (size_t)t * 512 + k0;
            unsigned short* d = &sB[t * ASTRIDE];
#pragma unroll
            for (int j = 0; j < 4; ++j) {
                bf16x8_t v = *(const bf16x8_t*)(src + j * 8);
                *(bf16x4_t*)(d + j * 8)     = __builtin_shufflevector(v, v, 0, 1, 2, 3);
                *(bf16x4_t*)(d + j * 8 + 4) = __builtin_shufflevector(v, v, 4, 5, 6, 7);
            }
        }
        __syncthreads();
        bf16x8_t a0, a1;
        {
            const unsigned short* p = &sAm[m_lo * ASTRIDE + quad * 8];
            bf16x4_t lo = *(const bf16x4_t*)p, hi = *(const bf16x4_t*)(p + 4);
            a0 = __builtin_shufflevector(lo, hi, 0, 1, 2, 3, 4, 5, 6, 7);
            p += 16 * ASTRIDE;
            lo = *(const bf16x4_t*)p; hi = *(const bf16x4_t*)(p + 4);
            a1 = __builtin_shufflevector(lo, hi, 0, 1, 2, 3, 4, 5, 6, 7);
        }
#pragma unroll
        for (int nt = 0; nt < 4; ++nt) {
            const unsigned short* p = &sB[(w * 64 + nt * 16 + m_lo) * ASTRIDE + quad * 8];
            bf16x4_t lo = *(const bf16x4_t*)p, hi = *(const bf16x4_t*)(p + 4);
            bf16x8_t b = __builtin_shufflevector(lo, hi, 0, 1, 2, 3, 4, 5, 6, 7);
            acc[0][nt] = MFMA16(a0, b, acc[0][nt]);
            acc[1][nt] = MFMA16(a1, b, acc[1][nt]);
        }
    }

#pragma unroll
    for (int mt = 0; mt < 2; ++mt)
#pragma unroll
        for (int nt = 0; nt < 4; ++nt) {
            const int col = w * 64 + nt * 16 + m_lo;
#pragma unroll
            for (int r = 0; r < 4; ++r) {
                const int row = row0 + mt * 16 + quad * 4 + r;
                out[(size_t)row * 256 + col] = tanhf(acc[mt][nt][r] + sBias[col]);
            }
        }
}

// ---------------------------------------------------------------------------
extern "C" void kernel_launch(void* const* d_in, const int* in_sizes, int n_in,
                              void* d_out, int out_size, void* d_ws, size_t ws_size,
                              hipStream_t stream) {
    const float* features = (const float*)d_in[0];
    const float* key      = (const float*)d_in[1];
    const float* adj      = (const float*)d_in[2];
    const float* W_d  = (const float*)d_in[3];
    const float* b_d  = (const float*)d_in[4];
    const float* W_o  = (const float*)d_in[5];
    const float* b_o  = (const float*)d_in[6];
    const float* W_a  = (const float*)d_in[7];
    const float* b_a  = (const float*)d_in[8];
    const float* W_ao = (const float*)d_in[9];
    const float* b_ao = (const float*)d_in[10];

    float* out1 = (float*)d_out;
    float* out2 = out1 + (size_t)8192 * 256;

    char* ws = (char*)d_ws;
    unsigned short* XcatN = (unsigned short*)(ws);                 // [8192][512] bf16, 8 MB
    unsigned short* Kcat  = (unsigned short*)(ws +  8388608);      // [8192][512] bf16, 8 MB
    unsigned short* Xtb   = (unsigned short*)(ws + 16777216);      // fragment blobs, 8 MB
    unsigned*       UpartB= (unsigned*)      (ws + 25165824);      // blocked [4][128][4][4096] u32, 32 MB
    float*          sSp   = (float*)         (ws + 58720256);      // [4][8192] f32
    unsigned short* W1t   = (unsigned short*)(ws + 58851328);      // [256][512] bf16
    unsigned short* W2t   = (unsigned short*)(ws + 59113472);      // [256][512] bf16
    float*          c1    = (float*)         (ws + 59375616);      // [256]
    float*          c2    = (float*)         (ws + 59376640);      // [256]

    dim3 blk(256);
    transpose_blob<<<dim3(256, 8), blk, 0, stream>>>(features, Xtb, (unsigned*)XcatN, 0);
    transpose_blob<<<dim3(256, 8), blk, 0, stream>>>(key, Xtb, (unsigned*)Kcat, 8);
    compose1<<<513, blk, 0, stream>>>(W_d, W_o, b_d, b_o, W1t, c1);
    compose2<<<513, blk, 0, stream>>>(W_a, W_ao, b_a, b_ao, W2t, c2);

    exp_gemm<<<512, dim3(512), 0, stream>>>(adj, Xtb, UpartB, sSp);
    finalize_agg<<<1024, blk, 0, stream>>>(UpartB, sSp,
                                           (unsigned*)XcatN, (unsigned*)Kcat);

    gemm_out<<<512, blk, 0, stream>>>(XcatN, W1t, c1, Kcat, W2t, c2, out1, out2);
}